// Round 8
// baseline (2363.030 us; speedup 1.0000x reference)
//
#include <hip/hip_runtime.h>
#include <stdint.h>

// Sparse 3D conv net, fp32, compact-row storage.
// occ0 (128^3) ~7% occupied, occ1 (64^3) ~44%, occ2/occ3 ~99-100% (dense).
// Sparse levels store features as compact rows + an idx map voxel->row+1.
// conv1/2/3: one thread per occupied output voxel (from compacted list),
// taps resolved through the input-level idx map (empty -> zero block).
// conv4/5/6: dense over 32^3/16^3, masked by occ at output level.

#define LIST_CAP 150016

static inline size_t al256(size_t x) { return (x + 255) & ~(size_t)255; }

__global__ __launch_bounds__(256) void scatter_occ_kernel(
    const int* __restrict__ coords, unsigned char* __restrict__ occ0, int n) {
  int t = blockIdx.x * 256 + threadIdx.x;
  if (t >= n) return;
  int i = coords[t * 3 + 0], j = coords[t * 3 + 1], k = coords[t * 3 + 2];
  occ0[(i * 128 + j) * 128 + k] = 1;
}

__global__ __launch_bounds__(256) void scatter_feat_kernel(
    const int* __restrict__ coords, const float* __restrict__ feats,
    const int* __restrict__ idx0, float* __restrict__ x0c, int n) {
  int t = blockIdx.x * 256 + threadIdx.x;
  if (t >= n) return;
  int i = coords[t * 3 + 0], j = coords[t * 3 + 1], k = coords[t * 3 + 2];
  int row = idx0[(i * 128 + j) * 128 + k] - 1;  // always occupied
  atomicAdd(&x0c[(size_t)row * 3 + 0], feats[t * 3 + 0]);
  atomicAdd(&x0c[(size_t)row * 3 + 1], feats[t * 3 + 1]);
  atomicAdd(&x0c[(size_t)row * 3 + 2], feats[t * 3 + 2]);
}

template <int LOUT>
__global__ __launch_bounds__(256) void pool_kernel(
    const unsigned char* __restrict__ in, unsigned char* __restrict__ out) {
  int t = blockIdx.x * 256 + threadIdx.x;
  if (t >= LOUT * LOUT * LOUT) return;
  int ox = t & (LOUT - 1);
  int oy = (t / LOUT) & (LOUT - 1);
  int oz = t / (LOUT * LOUT);
  const int LIN = LOUT * 2;
  unsigned char r = 0;
#pragma unroll
  for (int dz = 0; dz < 2; ++dz)
#pragma unroll
    for (int dy = 0; dy < 2; ++dy)
#pragma unroll
      for (int dx = 0; dx < 2; ++dx)
        r |= in[((size_t)(2 * oz + dz) * LIN + (2 * oy + dy)) * LIN + (2 * ox + dx)];
  out[t] = r ? 1 : 0;
}

// Builds compacted voxel list AND voxel->row+1 idx map (idx pre-zeroed).
__global__ __launch_bounds__(256) void compact_idx_kernel(
    const unsigned char* __restrict__ occ, int n, unsigned* __restrict__ list,
    int* __restrict__ idx, unsigned* __restrict__ cnt) {
  int v = blockIdx.x * 256 + threadIdx.x;
  bool a = (v < n) && (occ[v] != 0);
  unsigned long long m = __ballot(a);
  if (m == 0ull) return;
  int lane = threadIdx.x & 63;
  int leader = __builtin_ctzll(m);
  unsigned base = 0;
  if (lane == leader) base = atomicAdd(cnt, (unsigned)__popcll(m));
  base = __shfl(base, leader, 64);
  if (a) {
    unsigned pos = base + (unsigned)__popcll(m & ((1ull << lane) - 1ull));
    list[pos] = (unsigned)v;
    idx[v] = (int)pos + 1;
  }
}

template <int CI, int CO>
__device__ __forceinline__ void acc_tap(const float* __restrict__ src,
                                        const float* __restrict__ wt,
                                        float* acc) {
  if constexpr (CI % 4 == 0) {
#pragma unroll 4
    for (int ci = 0; ci < CI; ci += 4) {
      float4 x4 = *reinterpret_cast<const float4*>(src + ci);
      float xs[4] = {x4.x, x4.y, x4.z, x4.w};
#pragma unroll
      for (int u = 0; u < 4; ++u)
#pragma unroll
        for (int co = 0; co < CO; ++co)
          acc[co] = fmaf(xs[u], wt[(ci + u) * CO + co], acc[co]);
    }
  } else {
#pragma unroll
    for (int ci = 0; ci < CI; ++ci) {
      float xv = src[ci];
#pragma unroll
      for (int co = 0; co < CO; ++co)
        acc[co] = fmaf(xv, wt[ci * CO + co], acc[co]);
    }
  }
}

// Sparse conv: outputs = compacted list at resolution LOUT=LIN/STRIDE,
// input rows via idx_in (LIN^3 -> row+1), both compact storage.
template <int CI, int CO, int LIN, int STRIDE, bool RELU>
__global__ __launch_bounds__(256) void conv_sparse_kernel(
    const float* __restrict__ in, const int* __restrict__ idx_in,
    const float* __restrict__ w, const float* __restrict__ bias,
    const unsigned* __restrict__ list, const unsigned* __restrict__ cnt,
    const float* __restrict__ zeroblk, float* __restrict__ out) {
  int t = blockIdx.x * 256 + threadIdx.x;
  if (t >= (int)(*cnt)) return;
  constexpr int LOUT = LIN / STRIDE;
  constexpr int LB = (LOUT == 128) ? 7 : 6;
  unsigned v = list[t];
  int ox = (int)(v & (LOUT - 1));
  int oy = (int)((v >> LB) & (LOUT - 1));
  int oz = (int)(v >> (2 * LB));

  float acc[CO];
#pragma unroll
  for (int c = 0; c < CO; ++c) acc[c] = bias[c];

#pragma unroll 1
  for (int dz = 0; dz < 3; ++dz) {
    int iz = oz * STRIDE + dz - 1;
#pragma unroll 1
    for (int dy = 0; dy < 3; ++dy) {
      int iy = oy * STRIDE + dy - 1;
#pragma unroll 1
      for (int dx = 0; dx < 3; ++dx) {
        int ix = ox * STRIDE + dx - 1;
        bool valid = ((unsigned)iz < (unsigned)LIN) &&
                     ((unsigned)iy < (unsigned)LIN) &&
                     ((unsigned)ix < (unsigned)LIN);
        int vin = (iz * LIN + iy) * LIN + ix;
        int slot = valid ? idx_in[vin] : 0;
        const float* src = slot ? (in + (size_t)(slot - 1) * CI) : zeroblk;
        const float* wt = w + (size_t)((dz * 3 + dy) * 3 + dx) * CI * CO;
        acc_tap<CI, CO>(src, wt, acc);
      }
    }
  }

  size_t base = (size_t)t * CO;
#pragma unroll
  for (int co = 0; co < CO; co += 4) {
    float4 r;
#pragma unroll
    for (int u = 0; u < 4; ++u) {
      float val = acc[co + u];
      if constexpr (RELU) val = fmaxf(val, 0.f);
      (&r.x)[u] = val;
    }
    *reinterpret_cast<float4*>(out + base + co) = r;
  }
}

// Dense conv over LOUT^3; input either compact via idx_in (GATED) or dense.
// Output dense, masked by occ_out byte map.
template <int CI, int CO, int LIN, int LOUT, int STRIDE, bool RELU, bool GATED>
__global__ __launch_bounds__(256) void conv_dense_kernel(
    const float* __restrict__ in, const int* __restrict__ idx_in,
    const float* __restrict__ w, const float* __restrict__ bias,
    const unsigned char* __restrict__ occ_out,
    const float* __restrict__ zeroblk, float* __restrict__ out) {
  int t = blockIdx.x * 256 + threadIdx.x;
  if (t >= LOUT * LOUT * LOUT) return;
  constexpr int LB = (LOUT == 32) ? 5 : 4;
  int ox = t & (LOUT - 1);
  int oy = (t >> LB) & (LOUT - 1);
  int oz = t >> (2 * LB);

  float acc[CO];
#pragma unroll
  for (int c = 0; c < CO; ++c) acc[c] = bias[c];

#pragma unroll 1
  for (int dz = 0; dz < 3; ++dz) {
    int iz = oz * STRIDE + dz - 1;
#pragma unroll 1
    for (int dy = 0; dy < 3; ++dy) {
      int iy = oy * STRIDE + dy - 1;
#pragma unroll 1
      for (int dx = 0; dx < 3; ++dx) {
        int ix = ox * STRIDE + dx - 1;
        bool valid = ((unsigned)iz < (unsigned)LIN) &&
                     ((unsigned)iy < (unsigned)LIN) &&
                     ((unsigned)ix < (unsigned)LIN);
        int vin = (iz * LIN + iy) * LIN + ix;
        const float* src;
        if constexpr (GATED) {
          int slot = valid ? idx_in[vin] : 0;
          src = slot ? (in + (size_t)(slot - 1) * CI) : zeroblk;
        } else {
          src = valid ? (in + (size_t)vin * CI) : zeroblk;
        }
        const float* wt = w + (size_t)((dz * 3 + dy) * 3 + dx) * CI * CO;
        acc_tap<CI, CO>(src, wt, acc);
      }
    }
  }

  float mask = (occ_out[t] != 0) ? 1.f : 0.f;
  size_t base = (size_t)t * CO;
#pragma unroll
  for (int co = 0; co < CO; co += 4) {
    float4 r;
#pragma unroll
    for (int u = 0; u < 4; ++u) {
      float val = acc[co + u] * mask;
      if constexpr (RELU) val = fmaxf(val, 0.f);
      (&r.x)[u] = val;
    }
    *reinterpret_cast<float4*>(out + base + co) = r;
  }
}

extern "C" void kernel_launch(void* const* d_in, const int* in_sizes, int n_in,
                              void* d_out, int out_size, void* d_ws, size_t ws_size,
                              hipStream_t stream) {
  const int* coords = (const int*)d_in[0];
  const float* feats = (const float*)d_in[1];
  const float* w1 = (const float*)d_in[2];
  const float* b1 = (const float*)d_in[3];
  const float* w2 = (const float*)d_in[4];
  const float* b2 = (const float*)d_in[5];
  const float* w3 = (const float*)d_in[6];
  const float* b3 = (const float*)d_in[7];
  const float* w4 = (const float*)d_in[8];
  const float* b4 = (const float*)d_in[9];
  const float* w5 = (const float*)d_in[10];
  const float* b5 = (const float*)d_in[11];
  const float* w6 = (const float*)d_in[12];
  const float* b6 = (const float*)d_in[13];
  const int npts = in_sizes[0] / 3;

  char* p = (char*)d_ws;
  size_t off = 0;
  auto alloc = [&](size_t bytes) {
    char* r = p + off;
    off = al256(off + bytes);
    return r;
  };
  unsigned* cnts = (unsigned*)alloc(256);                       // [0]=cnt0,[1]=cnt1
  unsigned char* occ0 = (unsigned char*)alloc(2097152);         // 128^3
  unsigned char* occ1 = (unsigned char*)alloc(262144);          // 64^3
  unsigned char* occ2 = (unsigned char*)alloc(32768);           // 32^3
  unsigned char* occ3 = (unsigned char*)alloc(4096);            // 16^3
  int* idx0 = (int*)alloc((size_t)2097152 * 4);                 // 8 MB
  int* idx1 = (int*)alloc((size_t)262144 * 4);                  // 1 MB
  unsigned* list0 = (unsigned*)alloc((size_t)LIST_CAP * 4);
  unsigned* list1 = (unsigned*)alloc((size_t)LIST_CAP * 4);
  float* zeroblk = (float*)alloc(512);
  float* x0c = (float*)alloc((size_t)LIST_CAP * 3 * 4);         // 1.8 MB
  float* y1c = (float*)alloc((size_t)LIST_CAP * 64 * 4);        // 38.4 MB
  float* y2c = (float*)alloc((size_t)LIST_CAP * 64 * 4);        // 38.4 MB
  float* y3c = y1c;                                             // alias: y1 dead after conv2
  float* y4 = (float*)alloc((size_t)32768 * 32 * 4);            // 4.2 MB
  float* y5 = (float*)alloc((size_t)32768 * 32 * 4);            // 4.2 MB

  if (ws_size < off) return;  // graceful fail (readable absmax) over page fault

  hipMemsetAsync(cnts, 0, 256, stream);
  hipMemsetAsync(occ0, 0, 2097152, stream);
  hipMemsetAsync(idx0, 0, (size_t)2097152 * 4, stream);
  hipMemsetAsync(idx1, 0, (size_t)262144 * 4, stream);
  hipMemsetAsync(zeroblk, 0, 512, stream);
  hipMemsetAsync(x0c, 0, (size_t)LIST_CAP * 3 * 4, stream);

  scatter_occ_kernel<<<(npts + 255) / 256, 256, 0, stream>>>(coords, occ0, npts);
  pool_kernel<64><<<262144 / 256, 256, 0, stream>>>(occ0, occ1);
  pool_kernel<32><<<32768 / 256, 256, 0, stream>>>(occ1, occ2);
  pool_kernel<16><<<4096 / 256, 256, 0, stream>>>(occ2, occ3);
  compact_idx_kernel<<<2097152 / 256, 256, 0, stream>>>(occ0, 2097152, list0, idx0, cnts + 0);
  compact_idx_kernel<<<262144 / 256, 256, 0, stream>>>(occ1, 262144, list1, idx1, cnts + 1);
  scatter_feat_kernel<<<(npts + 255) / 256, 256, 0, stream>>>(coords, feats, idx0, x0c, npts);

  const int NBLK = (LIST_CAP + 255) / 256;
  // conv1: 3->64, 128^3, s1, outputs = occ0 list (reference masks by occ0)
  conv_sparse_kernel<3, 64, 128, 1, false>
      <<<NBLK, 256, 0, stream>>>(x0c, idx0, w1, b1, list0, cnts + 0, zeroblk, y1c);
  // conv2: 64->64, 128^3 -> 64^3, s2, *occ1 then relu; input rows via idx0
  conv_sparse_kernel<64, 64, 128, 2, true>
      <<<NBLK, 256, 0, stream>>>(y1c, idx0, w2, b2, list1, cnts + 1, zeroblk, y2c);
  // conv3: 64->64, 64^3, s1, *occ1; input rows via idx1
  conv_sparse_kernel<64, 64, 64, 1, false>
      <<<NBLK, 256, 0, stream>>>(y2c, idx1, w3, b3, list1, cnts + 1, zeroblk, y3c);
  // conv4: 64->32, 64^3 -> 32^3, s2, *occ2 then relu; input rows via idx1
  conv_dense_kernel<64, 32, 64, 32, 2, true, true>
      <<<32768 / 256, 256, 0, stream>>>(y3c, idx1, w4, b4, occ2, zeroblk, y4);
  // conv5: 32->32, 32^3, s1, *occ2; dense input
  conv_dense_kernel<32, 32, 32, 32, 1, false, false>
      <<<32768 / 256, 256, 0, stream>>>(y4, nullptr, w5, b5, occ2, zeroblk, y5);
  // conv6: 32->32, 32^3 -> 16^3, s2, *occ3; dense input, writes d_out
  conv_dense_kernel<32, 32, 32, 16, 2, false, false>
      <<<4096 / 256, 256, 0, stream>>>(y5, nullptr, w6, b6, occ3, zeroblk, (float*)d_out);
}

// Round 9
// 1887.799 us; speedup vs baseline: 1.2517x; 1.2517x over previous
//
#include <hip/hip_runtime.h>
#include <stdint.h>

// Sparse 3D conv net, fp32, compact-row storage.
// R8 change: split CO across blocks (block-uniform co-chunk) to fix the two
// measured problems: acc[64] spill (VGPR_Count=44 < 64 accs) and grid-limited
// occupancy (586 blocks -> 21%). Chunk id comes from blockIdx so weight
// addresses remain wave-uniform (scalarizable); acc shrinks to 16/8/4 regs.

#define LIST_CAP 150016
constexpr int NVB_SP = (LIST_CAP + 255) / 256;  // 586 voxel-blocks for sparse convs

static inline size_t al256(size_t x) { return (x + 255) & ~(size_t)255; }

__global__ __launch_bounds__(256) void scatter_occ_kernel(
    const int* __restrict__ coords, unsigned char* __restrict__ occ0, int n) {
  int t = blockIdx.x * 256 + threadIdx.x;
  if (t >= n) return;
  int i = coords[t * 3 + 0], j = coords[t * 3 + 1], k = coords[t * 3 + 2];
  occ0[(i * 128 + j) * 128 + k] = 1;
}

__global__ __launch_bounds__(256) void scatter_feat_kernel(
    const int* __restrict__ coords, const float* __restrict__ feats,
    const int* __restrict__ idx0, float* __restrict__ x0c, int n) {
  int t = blockIdx.x * 256 + threadIdx.x;
  if (t >= n) return;
  int i = coords[t * 3 + 0], j = coords[t * 3 + 1], k = coords[t * 3 + 2];
  int row = idx0[(i * 128 + j) * 128 + k] - 1;  // always occupied
  atomicAdd(&x0c[(size_t)row * 3 + 0], feats[t * 3 + 0]);
  atomicAdd(&x0c[(size_t)row * 3 + 1], feats[t * 3 + 1]);
  atomicAdd(&x0c[(size_t)row * 3 + 2], feats[t * 3 + 2]);
}

template <int LOUT>
__global__ __launch_bounds__(256) void pool_kernel(
    const unsigned char* __restrict__ in, unsigned char* __restrict__ out) {
  int t = blockIdx.x * 256 + threadIdx.x;
  if (t >= LOUT * LOUT * LOUT) return;
  int ox = t & (LOUT - 1);
  int oy = (t / LOUT) & (LOUT - 1);
  int oz = t / (LOUT * LOUT);
  const int LIN = LOUT * 2;
  unsigned char r = 0;
#pragma unroll
  for (int dz = 0; dz < 2; ++dz)
#pragma unroll
    for (int dy = 0; dy < 2; ++dy)
#pragma unroll
      for (int dx = 0; dx < 2; ++dx)
        r |= in[((size_t)(2 * oz + dz) * LIN + (2 * oy + dy)) * LIN + (2 * ox + dx)];
  out[t] = r ? 1 : 0;
}

// Builds compacted voxel list AND voxel->row+1 idx map (idx pre-zeroed).
__global__ __launch_bounds__(256) void compact_idx_kernel(
    const unsigned char* __restrict__ occ, int n, unsigned* __restrict__ list,
    int* __restrict__ idx, unsigned* __restrict__ cnt) {
  int v = blockIdx.x * 256 + threadIdx.x;
  bool a = (v < n) && (occ[v] != 0);
  unsigned long long m = __ballot(a);
  if (m == 0ull) return;
  int lane = threadIdx.x & 63;
  int leader = __builtin_ctzll(m);
  unsigned base = 0;
  if (lane == leader) base = atomicAdd(cnt, (unsigned)__popcll(m));
  base = __shfl(base, leader, 64);
  if (a) {
    unsigned pos = base + (unsigned)__popcll(m & ((1ull << lane) - 1ull));
    list[pos] = (unsigned)v;
    idx[v] = (int)pos + 1;
  }
}

// Accumulate one tap into COCHUNK accumulators; wt points at this block's
// co-chunk within the tap's CI x CO weight slab (stride CO between ci rows).
template <int CI, int CO, int COCHUNK>
__device__ __forceinline__ void acc_tap_split(const float* __restrict__ src,
                                              const float* __restrict__ wt,
                                              float* acc) {
  if constexpr (CI % 4 == 0) {
#pragma unroll 4
    for (int ci = 0; ci < CI; ci += 4) {
      float4 x4 = *reinterpret_cast<const float4*>(src + ci);
      float xs[4] = {x4.x, x4.y, x4.z, x4.w};
#pragma unroll
      for (int u = 0; u < 4; ++u)
#pragma unroll
        for (int c = 0; c < COCHUNK; ++c)
          acc[c] = fmaf(xs[u], wt[(size_t)(ci + u) * CO + c], acc[c]);
    }
  } else {
#pragma unroll
    for (int ci = 0; ci < CI; ++ci) {
      float xv = src[ci];
#pragma unroll
      for (int c = 0; c < COCHUNK; ++c)
        acc[c] = fmaf(xv, wt[(size_t)ci * CO + c], acc[c]);
    }
  }
}

// Sparse conv, CO split across blocks: blockIdx = vb + NVB_SP * chunk.
// chunk is block-uniform -> weight addresses wave-uniform (scalarizable).
template <int CI, int CO, int COCHUNK, int LIN, int STRIDE, bool RELU>
__global__ __launch_bounds__(256, 4) void conv_sparse_split_kernel(
    const float* __restrict__ in, const int* __restrict__ idx_in,
    const float* __restrict__ w, const float* __restrict__ bias,
    const unsigned* __restrict__ list, const unsigned* __restrict__ cnt,
    const float* __restrict__ zeroblk, float* __restrict__ out) {
  constexpr int LOUT = LIN / STRIDE;
  constexpr int LB = (LOUT == 128) ? 7 : 6;
  int vb = (int)blockIdx.x % NVB_SP;
  int chunk = (int)blockIdx.x / NVB_SP;  // block-uniform co-chunk
  int t = vb * 256 + (int)threadIdx.x;
  if (t >= (int)(*cnt)) return;
  unsigned v = list[t];
  int ox = (int)(v & (LOUT - 1));
  int oy = (int)((v >> LB) & (LOUT - 1));
  int oz = (int)(v >> (2 * LB));

  const float* wc = w + chunk * COCHUNK;
  const float* bc = bias + chunk * COCHUNK;

  float acc[COCHUNK];
#pragma unroll
  for (int c = 0; c < COCHUNK; ++c) acc[c] = bc[c];

#pragma unroll 1
  for (int dz = 0; dz < 3; ++dz) {
    int iz = oz * STRIDE + dz - 1;
#pragma unroll 1
    for (int dy = 0; dy < 3; ++dy) {
      int iy = oy * STRIDE + dy - 1;
#pragma unroll 1
      for (int dx = 0; dx < 3; ++dx) {
        int ix = ox * STRIDE + dx - 1;
        bool valid = ((unsigned)iz < (unsigned)LIN) &&
                     ((unsigned)iy < (unsigned)LIN) &&
                     ((unsigned)ix < (unsigned)LIN);
        int vin = (iz * LIN + iy) * LIN + ix;
        int slot = valid ? idx_in[vin] : 0;
        const float* src = slot ? (in + (size_t)(slot - 1) * CI) : zeroblk;
        const float* wt = wc + (size_t)((dz * 3 + dy) * 3 + dx) * CI * CO;
        acc_tap_split<CI, CO, COCHUNK>(src, wt, acc);
      }
    }
  }

  size_t base = (size_t)t * CO + (size_t)chunk * COCHUNK;
#pragma unroll
  for (int c = 0; c < COCHUNK; c += 4) {
    float4 r;
#pragma unroll
    for (int u = 0; u < 4; ++u) {
      float val = acc[c + u];
      if constexpr (RELU) val = fmaxf(val, 0.f);
      (&r.x)[u] = val;
    }
    *reinterpret_cast<float4*>(out + base + c) = r;
  }
}

// Dense conv over LOUT^3, CO split across blocks like the sparse version.
template <int CI, int CO, int COCHUNK, int LIN, int LOUT, int STRIDE, bool RELU, bool GATED>
__global__ __launch_bounds__(256, 4) void conv_dense_split_kernel(
    const float* __restrict__ in, const int* __restrict__ idx_in,
    const float* __restrict__ w, const float* __restrict__ bias,
    const unsigned char* __restrict__ occ_out,
    const float* __restrict__ zeroblk, float* __restrict__ out) {
  constexpr int NVB = (LOUT * LOUT * LOUT) / 256;
  constexpr int LB = (LOUT == 32) ? 5 : 4;
  int vb = (int)blockIdx.x % NVB;
  int chunk = (int)blockIdx.x / NVB;  // block-uniform
  int vox = vb * 256 + (int)threadIdx.x;
  int ox = vox & (LOUT - 1);
  int oy = (vox >> LB) & (LOUT - 1);
  int oz = vox >> (2 * LB);

  const float* wc = w + chunk * COCHUNK;
  const float* bc = bias + chunk * COCHUNK;

  float acc[COCHUNK];
#pragma unroll
  for (int c = 0; c < COCHUNK; ++c) acc[c] = bc[c];

#pragma unroll 1
  for (int dz = 0; dz < 3; ++dz) {
    int iz = oz * STRIDE + dz - 1;
#pragma unroll 1
    for (int dy = 0; dy < 3; ++dy) {
      int iy = oy * STRIDE + dy - 1;
#pragma unroll 1
      for (int dx = 0; dx < 3; ++dx) {
        int ix = ox * STRIDE + dx - 1;
        bool valid = ((unsigned)iz < (unsigned)LIN) &&
                     ((unsigned)iy < (unsigned)LIN) &&
                     ((unsigned)ix < (unsigned)LIN);
        int vin = (iz * LIN + iy) * LIN + ix;
        const float* src;
        if constexpr (GATED) {
          int slot = valid ? idx_in[vin] : 0;
          src = slot ? (in + (size_t)(slot - 1) * CI) : zeroblk;
        } else {
          src = valid ? (in + (size_t)vin * CI) : zeroblk;
        }
        const float* wt = wc + (size_t)((dz * 3 + dy) * 3 + dx) * CI * CO;
        acc_tap_split<CI, CO, COCHUNK>(src, wt, acc);
      }
    }
  }

  float mask = (occ_out[vox] != 0) ? 1.f : 0.f;
  size_t base = (size_t)vox * CO + (size_t)chunk * COCHUNK;
#pragma unroll
  for (int c = 0; c < COCHUNK; c += 4) {
    float4 r;
#pragma unroll
    for (int u = 0; u < 4; ++u) {
      float val = acc[c + u] * mask;
      if constexpr (RELU) val = fmaxf(val, 0.f);
      (&r.x)[u] = val;
    }
    *reinterpret_cast<float4*>(out + base + c) = r;
  }
}

extern "C" void kernel_launch(void* const* d_in, const int* in_sizes, int n_in,
                              void* d_out, int out_size, void* d_ws, size_t ws_size,
                              hipStream_t stream) {
  const int* coords = (const int*)d_in[0];
  const float* feats = (const float*)d_in[1];
  const float* w1 = (const float*)d_in[2];
  const float* b1 = (const float*)d_in[3];
  const float* w2 = (const float*)d_in[4];
  const float* b2 = (const float*)d_in[5];
  const float* w3 = (const float*)d_in[6];
  const float* b3 = (const float*)d_in[7];
  const float* w4 = (const float*)d_in[8];
  const float* b4 = (const float*)d_in[9];
  const float* w5 = (const float*)d_in[10];
  const float* b5 = (const float*)d_in[11];
  const float* w6 = (const float*)d_in[12];
  const float* b6 = (const float*)d_in[13];
  const int npts = in_sizes[0] / 3;

  char* p = (char*)d_ws;
  size_t off = 0;
  auto alloc = [&](size_t bytes) {
    char* r = p + off;
    off = al256(off + bytes);
    return r;
  };
  unsigned* cnts = (unsigned*)alloc(256);                       // [0]=cnt0,[1]=cnt1
  unsigned char* occ0 = (unsigned char*)alloc(2097152);         // 128^3
  unsigned char* occ1 = (unsigned char*)alloc(262144);          // 64^3
  unsigned char* occ2 = (unsigned char*)alloc(32768);           // 32^3
  unsigned char* occ3 = (unsigned char*)alloc(4096);            // 16^3
  int* idx0 = (int*)alloc((size_t)2097152 * 4);                 // 8 MB
  int* idx1 = (int*)alloc((size_t)262144 * 4);                  // 1 MB
  unsigned* list0 = (unsigned*)alloc((size_t)LIST_CAP * 4);
  unsigned* list1 = (unsigned*)alloc((size_t)LIST_CAP * 4);
  float* zeroblk = (float*)alloc(512);
  float* x0c = (float*)alloc((size_t)LIST_CAP * 3 * 4);         // 1.8 MB
  float* y1c = (float*)alloc((size_t)LIST_CAP * 64 * 4);        // 38.4 MB
  float* y2c = (float*)alloc((size_t)LIST_CAP * 64 * 4);        // 38.4 MB
  float* y3c = y1c;                                             // alias: y1 dead after conv2
  float* y4 = (float*)alloc((size_t)32768 * 32 * 4);            // 4.2 MB
  float* y5 = (float*)alloc((size_t)32768 * 32 * 4);            // 4.2 MB

  if (ws_size < off) return;  // graceful fail (readable absmax) over page fault

  hipMemsetAsync(cnts, 0, 256, stream);
  hipMemsetAsync(occ0, 0, 2097152, stream);
  hipMemsetAsync(idx0, 0, (size_t)2097152 * 4, stream);
  hipMemsetAsync(idx1, 0, (size_t)262144 * 4, stream);
  hipMemsetAsync(zeroblk, 0, 512, stream);
  hipMemsetAsync(x0c, 0, (size_t)LIST_CAP * 3 * 4, stream);

  scatter_occ_kernel<<<(npts + 255) / 256, 256, 0, stream>>>(coords, occ0, npts);
  pool_kernel<64><<<262144 / 256, 256, 0, stream>>>(occ0, occ1);
  pool_kernel<32><<<32768 / 256, 256, 0, stream>>>(occ1, occ2);
  pool_kernel<16><<<4096 / 256, 256, 0, stream>>>(occ2, occ3);
  compact_idx_kernel<<<2097152 / 256, 256, 0, stream>>>(occ0, 2097152, list0, idx0, cnts + 0);
  compact_idx_kernel<<<262144 / 256, 256, 0, stream>>>(occ1, 262144, list1, idx1, cnts + 1);
  scatter_feat_kernel<<<(npts + 255) / 256, 256, 0, stream>>>(coords, feats, idx0, x0c, npts);

  // conv1: 3->64, 128^3, s1; CO split 4x16 -> 2344 blocks
  conv_sparse_split_kernel<3, 64, 16, 128, 1, false>
      <<<NVB_SP * 4, 256, 0, stream>>>(x0c, idx0, w1, b1, list0, cnts + 0, zeroblk, y1c);
  // conv2: 64->64, s2 -> 64^3, relu; CO split 4x16
  conv_sparse_split_kernel<64, 64, 16, 128, 2, true>
      <<<NVB_SP * 4, 256, 0, stream>>>(y1c, idx0, w2, b2, list1, cnts + 1, zeroblk, y2c);
  // conv3: 64->64, 64^3, s1; CO split 4x16
  conv_sparse_split_kernel<64, 64, 16, 64, 1, false>
      <<<NVB_SP * 4, 256, 0, stream>>>(y2c, idx1, w3, b3, list1, cnts + 1, zeroblk, y3c);
  // conv4: 64->32, 64^3 -> 32^3, s2, relu; CO split 4x8 -> 512 blocks
  conv_dense_split_kernel<64, 32, 8, 64, 32, 2, true, true>
      <<<(32768 / 256) * 4, 256, 0, stream>>>(y3c, idx1, w4, b4, occ2, zeroblk, y4);
  // conv5: 32->32, 32^3, s1; CO split 4x8 -> 512 blocks
  conv_dense_split_kernel<32, 32, 8, 32, 32, 1, false, false>
      <<<(32768 / 256) * 4, 256, 0, stream>>>(y4, nullptr, w5, b5, occ2, zeroblk, y5);
  // conv6: 32->32, 32^3 -> 16^3, s2; CO split 8x4 -> 128 blocks
  conv_dense_split_kernel<32, 32, 4, 32, 16, 2, false, false>
      <<<(4096 / 256) * 8, 256, 0, stream>>>(y5, nullptr, w6, b6, occ3, zeroblk, (float*)d_out);
}

// Round 10
// 1758.590 us; speedup vs baseline: 1.3437x; 1.0735x over previous
//
#include <hip/hip_runtime.h>
#include <stdint.h>

// Sparse 3D conv net, fp32, compact-row storage.
// R9 change: VOX=2 voxel register-blocking in sparse convs. Measured (R8->R9
// bench): spill fixed (VGPR 24) and occupancy 45%, but VALUBusy stuck ~30% ->
// per-wave latency-bound on gathered src loads. Two independent gather
// streams per thread double MLP; each scalarized weight feeds 2x FMAs.

#define LIST_CAP 150016

static inline size_t al256(size_t x) { return (x + 255) & ~(size_t)255; }

__global__ __launch_bounds__(256) void scatter_occ_kernel(
    const int* __restrict__ coords, unsigned char* __restrict__ occ0, int n) {
  int t = blockIdx.x * 256 + threadIdx.x;
  if (t >= n) return;
  int i = coords[t * 3 + 0], j = coords[t * 3 + 1], k = coords[t * 3 + 2];
  occ0[(i * 128 + j) * 128 + k] = 1;
}

__global__ __launch_bounds__(256) void scatter_feat_kernel(
    const int* __restrict__ coords, const float* __restrict__ feats,
    const int* __restrict__ idx0, float* __restrict__ x0c, int n) {
  int t = blockIdx.x * 256 + threadIdx.x;
  if (t >= n) return;
  int i = coords[t * 3 + 0], j = coords[t * 3 + 1], k = coords[t * 3 + 2];
  int row = idx0[(i * 128 + j) * 128 + k] - 1;  // always occupied
  atomicAdd(&x0c[(size_t)row * 3 + 0], feats[t * 3 + 0]);
  atomicAdd(&x0c[(size_t)row * 3 + 1], feats[t * 3 + 1]);
  atomicAdd(&x0c[(size_t)row * 3 + 2], feats[t * 3 + 2]);
}

template <int LOUT>
__global__ __launch_bounds__(256) void pool_kernel(
    const unsigned char* __restrict__ in, unsigned char* __restrict__ out) {
  int t = blockIdx.x * 256 + threadIdx.x;
  if (t >= LOUT * LOUT * LOUT) return;
  int ox = t & (LOUT - 1);
  int oy = (t / LOUT) & (LOUT - 1);
  int oz = t / (LOUT * LOUT);
  const int LIN = LOUT * 2;
  unsigned char r = 0;
#pragma unroll
  for (int dz = 0; dz < 2; ++dz)
#pragma unroll
    for (int dy = 0; dy < 2; ++dy)
#pragma unroll
      for (int dx = 0; dx < 2; ++dx)
        r |= in[((size_t)(2 * oz + dz) * LIN + (2 * oy + dy)) * LIN + (2 * ox + dx)];
  out[t] = r ? 1 : 0;
}

// Builds compacted voxel list AND voxel->row+1 idx map (idx pre-zeroed).
__global__ __launch_bounds__(256) void compact_idx_kernel(
    const unsigned char* __restrict__ occ, int n, unsigned* __restrict__ list,
    int* __restrict__ idx, unsigned* __restrict__ cnt) {
  int v = blockIdx.x * 256 + threadIdx.x;
  bool a = (v < n) && (occ[v] != 0);
  unsigned long long m = __ballot(a);
  if (m == 0ull) return;
  int lane = threadIdx.x & 63;
  int leader = __builtin_ctzll(m);
  unsigned base = 0;
  if (lane == leader) base = atomicAdd(cnt, (unsigned)__popcll(m));
  base = __shfl(base, leader, 64);
  if (a) {
    unsigned pos = base + (unsigned)__popcll(m & ((1ull << lane) - 1ull));
    list[pos] = (unsigned)v;
    idx[v] = (int)pos + 1;
  }
}

// Sparse conv, CO split across blocks AND VOX voxels per thread.
// blockIdx = vb + NVB * chunk; thread handles list rows t0, t0+256, ...
template <int CI, int CO, int COCHUNK, int VOX, int LIN, int STRIDE, bool RELU>
__global__ __launch_bounds__(256, 4) void conv_sparse_split_kernel(
    const float* __restrict__ in, const int* __restrict__ idx_in,
    const float* __restrict__ w, const float* __restrict__ bias,
    const unsigned* __restrict__ list, const unsigned* __restrict__ cnt,
    const float* __restrict__ zeroblk, float* __restrict__ out) {
  constexpr int LOUT = LIN / STRIDE;
  constexpr int LB = (LOUT == 128) ? 7 : 6;
  constexpr int NVB = (LIST_CAP + 256 * VOX - 1) / (256 * VOX);
  int vb = (int)blockIdx.x % NVB;
  int chunk = (int)blockIdx.x / NVB;  // block-uniform co-chunk
  int n = (int)(*cnt);
  int t0 = vb * (256 * VOX) + (int)threadIdx.x;
  if (t0 >= n) return;

  const float* wc = w + chunk * COCHUNK;
  const float* bc = bias + chunk * COCHUNK;

  int tt[VOX];
  bool act[VOX];
  int ox[VOX], oy[VOX], oz[VOX];
#pragma unroll
  for (int vx = 0; vx < VOX; ++vx) {
    tt[vx] = t0 + vx * 256;
    act[vx] = tt[vx] < n;
    unsigned v = act[vx] ? list[tt[vx]] : 0u;
    ox[vx] = (int)(v & (LOUT - 1));
    oy[vx] = (int)((v >> LB) & (LOUT - 1));
    oz[vx] = (int)(v >> (2 * LB));
  }

  float acc[VOX][COCHUNK];
#pragma unroll
  for (int vx = 0; vx < VOX; ++vx)
#pragma unroll
    for (int c = 0; c < COCHUNK; ++c) acc[vx][c] = bc[c];

#pragma unroll 1
  for (int dz = 0; dz < 3; ++dz) {
#pragma unroll 1
    for (int dy = 0; dy < 3; ++dy) {
#pragma unroll 1
      for (int dx = 0; dx < 3; ++dx) {
        const float* src[VOX];
#pragma unroll
        for (int vx = 0; vx < VOX; ++vx) {
          int iz = oz[vx] * STRIDE + dz - 1;
          int iy = oy[vx] * STRIDE + dy - 1;
          int ix = ox[vx] * STRIDE + dx - 1;
          bool valid = act[vx] && ((unsigned)iz < (unsigned)LIN) &&
                       ((unsigned)iy < (unsigned)LIN) &&
                       ((unsigned)ix < (unsigned)LIN);
          int vin = (iz * LIN + iy) * LIN + ix;
          int slot = valid ? idx_in[vin] : 0;
          src[vx] = slot ? (in + (size_t)(slot - 1) * CI) : zeroblk;
        }
        const float* wt = wc + (size_t)((dz * 3 + dy) * 3 + dx) * CI * CO;
        if constexpr (CI % 4 == 0) {
#pragma unroll 4
          for (int ci = 0; ci < CI; ci += 4) {
            float4 x4[VOX];
#pragma unroll
            for (int vx = 0; vx < VOX; ++vx)
              x4[vx] = *reinterpret_cast<const float4*>(src[vx] + ci);
#pragma unroll
            for (int u = 0; u < 4; ++u) {
#pragma unroll
              for (int c = 0; c < COCHUNK; ++c) {
                float wv = wt[(size_t)(ci + u) * CO + c];
#pragma unroll
                for (int vx = 0; vx < VOX; ++vx)
                  acc[vx][c] = fmaf((&x4[vx].x)[u], wv, acc[vx][c]);
              }
            }
          }
        } else {
#pragma unroll
          for (int ci = 0; ci < CI; ++ci) {
            float xv[VOX];
#pragma unroll
            for (int vx = 0; vx < VOX; ++vx) xv[vx] = src[vx][ci];
#pragma unroll
            for (int c = 0; c < COCHUNK; ++c) {
              float wv = wt[(size_t)ci * CO + c];
#pragma unroll
              for (int vx = 0; vx < VOX; ++vx)
                acc[vx][c] = fmaf(xv[vx], wv, acc[vx][c]);
            }
          }
        }
      }
    }
  }

#pragma unroll
  for (int vx = 0; vx < VOX; ++vx) {
    if (!act[vx]) continue;
    size_t base = (size_t)tt[vx] * CO + (size_t)chunk * COCHUNK;
#pragma unroll
    for (int c = 0; c < COCHUNK; c += 4) {
      float4 r;
#pragma unroll
      for (int u = 0; u < 4; ++u) {
        float val = acc[vx][c + u];
        if constexpr (RELU) val = fmaxf(val, 0.f);
        (&r.x)[u] = val;
      }
      *reinterpret_cast<float4*>(out + base + c) = r;
    }
  }
}

// Dense conv over LOUT^3, CO split across blocks (unchanged from R8).
template <int CI, int CO, int COCHUNK, int LIN, int LOUT, int STRIDE, bool RELU, bool GATED>
__global__ __launch_bounds__(256, 4) void conv_dense_split_kernel(
    const float* __restrict__ in, const int* __restrict__ idx_in,
    const float* __restrict__ w, const float* __restrict__ bias,
    const unsigned char* __restrict__ occ_out,
    const float* __restrict__ zeroblk, float* __restrict__ out) {
  constexpr int NVB = (LOUT * LOUT * LOUT) / 256;
  constexpr int LB = (LOUT == 32) ? 5 : 4;
  int vb = (int)blockIdx.x % NVB;
  int chunk = (int)blockIdx.x / NVB;  // block-uniform
  int vox = vb * 256 + (int)threadIdx.x;
  int ox = vox & (LOUT - 1);
  int oy = (vox >> LB) & (LOUT - 1);
  int oz = vox >> (2 * LB);

  const float* wc = w + chunk * COCHUNK;
  const float* bc = bias + chunk * COCHUNK;

  float acc[COCHUNK];
#pragma unroll
  for (int c = 0; c < COCHUNK; ++c) acc[c] = bc[c];

#pragma unroll 1
  for (int dz = 0; dz < 3; ++dz) {
    int iz = oz * STRIDE + dz - 1;
#pragma unroll 1
    for (int dy = 0; dy < 3; ++dy) {
      int iy = oy * STRIDE + dy - 1;
#pragma unroll 1
      for (int dx = 0; dx < 3; ++dx) {
        int ix = ox * STRIDE + dx - 1;
        bool valid = ((unsigned)iz < (unsigned)LIN) &&
                     ((unsigned)iy < (unsigned)LIN) &&
                     ((unsigned)ix < (unsigned)LIN);
        int vin = (iz * LIN + iy) * LIN + ix;
        const float* src;
        if constexpr (GATED) {
          int slot = valid ? idx_in[vin] : 0;
          src = slot ? (in + (size_t)(slot - 1) * CI) : zeroblk;
        } else {
          src = valid ? (in + (size_t)vin * CI) : zeroblk;
        }
        const float* wt = wc + (size_t)((dz * 3 + dy) * 3 + dx) * CI * CO;
#pragma unroll 4
        for (int ci = 0; ci < CI; ci += 4) {
          float4 x4 = *reinterpret_cast<const float4*>(src + ci);
          float xs[4] = {x4.x, x4.y, x4.z, x4.w};
#pragma unroll
          for (int u = 0; u < 4; ++u)
#pragma unroll
            for (int c = 0; c < COCHUNK; ++c)
              acc[c] = fmaf(xs[u], wt[(size_t)(ci + u) * CO + c], acc[c]);
        }
      }
    }
  }

  float mask = (occ_out[vox] != 0) ? 1.f : 0.f;
  size_t base = (size_t)vox * CO + (size_t)chunk * COCHUNK;
#pragma unroll
  for (int c = 0; c < COCHUNK; c += 4) {
    float4 r;
#pragma unroll
    for (int u = 0; u < 4; ++u) {
      float val = acc[c + u] * mask;
      if constexpr (RELU) val = fmaxf(val, 0.f);
      (&r.x)[u] = val;
    }
    *reinterpret_cast<float4*>(out + base + c) = r;
  }
}

extern "C" void kernel_launch(void* const* d_in, const int* in_sizes, int n_in,
                              void* d_out, int out_size, void* d_ws, size_t ws_size,
                              hipStream_t stream) {
  const int* coords = (const int*)d_in[0];
  const float* feats = (const float*)d_in[1];
  const float* w1 = (const float*)d_in[2];
  const float* b1 = (const float*)d_in[3];
  const float* w2 = (const float*)d_in[4];
  const float* b2 = (const float*)d_in[5];
  const float* w3 = (const float*)d_in[6];
  const float* b3 = (const float*)d_in[7];
  const float* w4 = (const float*)d_in[8];
  const float* b4 = (const float*)d_in[9];
  const float* w5 = (const float*)d_in[10];
  const float* b5 = (const float*)d_in[11];
  const float* w6 = (const float*)d_in[12];
  const float* b6 = (const float*)d_in[13];
  const int npts = in_sizes[0] / 3;

  char* p = (char*)d_ws;
  size_t off = 0;
  auto alloc = [&](size_t bytes) {
    char* r = p + off;
    off = al256(off + bytes);
    return r;
  };
  unsigned* cnts = (unsigned*)alloc(256);                       // [0]=cnt0,[1]=cnt1
  unsigned char* occ0 = (unsigned char*)alloc(2097152);         // 128^3
  unsigned char* occ1 = (unsigned char*)alloc(262144);          // 64^3
  unsigned char* occ2 = (unsigned char*)alloc(32768);           // 32^3
  unsigned char* occ3 = (unsigned char*)alloc(4096);            // 16^3
  int* idx0 = (int*)alloc((size_t)2097152 * 4);                 // 8 MB
  int* idx1 = (int*)alloc((size_t)262144 * 4);                  // 1 MB
  unsigned* list0 = (unsigned*)alloc((size_t)LIST_CAP * 4);
  unsigned* list1 = (unsigned*)alloc((size_t)LIST_CAP * 4);
  float* zeroblk = (float*)alloc(512);
  float* x0c = (float*)alloc((size_t)LIST_CAP * 3 * 4);         // 1.8 MB
  float* y1c = (float*)alloc((size_t)LIST_CAP * 64 * 4);        // 38.4 MB
  float* y2c = (float*)alloc((size_t)LIST_CAP * 64 * 4);        // 38.4 MB
  float* y3c = y1c;                                             // alias: y1 dead after conv2
  float* y4 = (float*)alloc((size_t)32768 * 32 * 4);            // 4.2 MB
  float* y5 = (float*)alloc((size_t)32768 * 32 * 4);            // 4.2 MB

  if (ws_size < off) return;  // graceful fail (readable absmax) over page fault

  hipMemsetAsync(cnts, 0, 256, stream);
  hipMemsetAsync(occ0, 0, 2097152, stream);
  hipMemsetAsync(idx0, 0, (size_t)2097152 * 4, stream);
  hipMemsetAsync(idx1, 0, (size_t)262144 * 4, stream);
  hipMemsetAsync(zeroblk, 0, 512, stream);
  hipMemsetAsync(x0c, 0, (size_t)LIST_CAP * 3 * 4, stream);

  scatter_occ_kernel<<<(npts + 255) / 256, 256, 0, stream>>>(coords, occ0, npts);
  pool_kernel<64><<<262144 / 256, 256, 0, stream>>>(occ0, occ1);
  pool_kernel<32><<<32768 / 256, 256, 0, stream>>>(occ1, occ2);
  pool_kernel<16><<<4096 / 256, 256, 0, stream>>>(occ2, occ3);
  compact_idx_kernel<<<2097152 / 256, 256, 0, stream>>>(occ0, 2097152, list0, idx0, cnts + 0);
  compact_idx_kernel<<<262144 / 256, 256, 0, stream>>>(occ1, 262144, list1, idx1, cnts + 1);
  scatter_feat_kernel<<<(npts + 255) / 256, 256, 0, stream>>>(coords, feats, idx0, x0c, npts);

  constexpr int NVB2 = (LIST_CAP + 511) / 512;  // VOX=2 voxel-blocks: 293
  // conv1: 3->64, 128^3, s1; CO split 4x16, VOX=2 -> 1172 blocks
  conv_sparse_split_kernel<3, 64, 16, 2, 128, 1, false>
      <<<NVB2 * 4, 256, 0, stream>>>(x0c, idx0, w1, b1, list0, cnts + 0, zeroblk, y1c);
  // conv2: 64->64, s2 -> 64^3, relu; CO split 4x16, VOX=2
  conv_sparse_split_kernel<64, 64, 16, 2, 128, 2, true>
      <<<NVB2 * 4, 256, 0, stream>>>(y1c, idx0, w2, b2, list1, cnts + 1, zeroblk, y2c);
  // conv3: 64->64, 64^3, s1; CO split 4x16, VOX=2
  conv_sparse_split_kernel<64, 64, 16, 2, 64, 1, false>
      <<<NVB2 * 4, 256, 0, stream>>>(y2c, idx1, w3, b3, list1, cnts + 1, zeroblk, y3c);
  // conv4: 64->32, 64^3 -> 32^3, s2, relu; CO split 4x8 -> 512 blocks
  conv_dense_split_kernel<64, 32, 8, 64, 32, 2, true, true>
      <<<(32768 / 256) * 4, 256, 0, stream>>>(y3c, idx1, w4, b4, occ2, zeroblk, y4);
  // conv5: 32->32, 32^3, s1; CO split 4x8 -> 512 blocks
  conv_dense_split_kernel<32, 32, 8, 32, 32, 1, false, false>
      <<<(32768 / 256) * 4, 256, 0, stream>>>(y4, nullptr, w5, b5, occ2, zeroblk, y5);
  // conv6: 32->32, 32^3 -> 16^3, s2; CO split 8x4 -> 128 blocks
  conv_dense_split_kernel<32, 32, 4, 32, 16, 2, false, false>
      <<<(4096 / 256) * 8, 256, 0, stream>>>(y5, nullptr, w6, b6, occ3, zeroblk, (float*)d_out);
}